// Round 13
// baseline (103.548 us; speedup 1.0000x reference)
//
#include <hip/hip_runtime.h>

#define WI 4096
#define HI 4096
#define WO 4090
#define HO 4090
#define TH 8             // output rows per block
#define IH 14            // staged input rows
#define IWP 512          // floats per LDS row == staged window (shift/mask!)
#define CW 506           // computed output cols per block
#define NCHK (IH*128)    // total 16B chunks = 1792 = 7 per thread

__device__ __forceinline__ void gl_lds16(const float* g, float* l) {
    __builtin_amdgcn_global_load_lds(
        (const __attribute__((address_space(1))) void*)g,
        (__attribute__((address_space(3))) void*)l, 16, 0, 0);
}

__global__ __launch_bounds__(256, 5) void conv7x7(
    const float* __restrict__ x, const float* __restrict__ wgt,
    const float* __restrict__ bias, float* __restrict__ out)
{
    __shared__ float lds[IH * IWP];   // 28,672 B -> 5 blocks/CU (20 waves)

    const int tid = threadIdx.x;
    const int x0  = blockIdx.x * CW;      // stripe start col
    const int y0  = blockIdx.y * TH;

    // weights + bias: uniform addresses -> SGPR-resident scalar loads
    float Wt[49];
    #pragma unroll
    for (int i = 0; i < 49; ++i) Wt[i] = wgt[i];
    const float bb = bias[0];

    const int cx   = 2 * tid;                       // local col pair
    const int cxr  = cx <= 504 ? cx : 504;          // clamped LDS read col
    const int gx   = x0 + cx;
    const bool stok = (cx <= 504) && (gx + 1 < WO); // pair-store mask

    // stage chunks [k0,kn) x 256 threads: chunk c = tid + 256k ->
    // LDS floats [4c,4c+4), src row c>>7, col 4*(c&127). Pure shift/mask.
    // LDS dest per wave-instr = uniform base + lane*16 (linear, required).
    // Per-lane clamped sources only feed masked-off outputs.
    auto stage = [&](int k0, int kn) {
        #pragma unroll
        for (int k = k0; k < kn; ++k) {
            const int c  = tid + (k << 8);
            const int rr = c >> 7;
            int gy = y0 + rr;            gy  = gy  < HI ? gy : HI - 1;
            int gxs = x0 + ((c & 127) << 2); gxs = gxs <= WI - 4 ? gxs : WI - 4;
            gl_lds16(x + (size_t)gy * WI + gxs, lds + c * 4);
        }
    };

    float a0[7], a1[7];
    #pragma unroll
    for (int s = 0; s < 7; ++s) { a0[s] = 0.f; a1[s] = 0.f; }

    // fully-static row step: 4x ds_read_b64 + 98 FMA + (from r>=6) 1 store
    #define DOROW(r)                                                        \
    {                                                                       \
        const float* lrow_ = lds + (r) * IWP + cxr;                         \
        const float2 q0 = *(const float2*)(lrow_ + 0);                      \
        const float2 q1 = *(const float2*)(lrow_ + 2);                      \
        const float2 q2 = *(const float2*)(lrow_ + 4);                      \
        const float2 q3 = *(const float2*)(lrow_ + 6);                      \
        const float f_[8] = {q0.x,q0.y,q1.x,q1.y,q2.x,q2.y,q3.x,q3.y};      \
        _Pragma("unroll")                                                   \
        for (int ky = 0; ky < 7; ++ky) {                                    \
            const int oy = (r) - ky;               /* static */             \
            if (oy >= 0 && oy < TH) {                                       \
                const int s = oy % 7;              /* static */             \
                _Pragma("unroll")                                           \
                for (int kx = 0; kx < 7; ++kx) {                            \
                    const float w_ = Wt[ky * 7 + kx];                       \
                    a0[s] += w_ * f_[kx];                                   \
                    a1[s] += w_ * f_[kx + 1];                               \
                }                                                           \
            }                                                               \
        }                                                                   \
        if ((r) >= 6) {                            /* static */             \
            const int oy = (r) - 6;                                         \
            const int s  = oy % 7;                 /* static */             \
            const int gy = y0 + oy;                                         \
            if (stok && gy < HO) {                                          \
                float2 o_; o_.x = a0[s] + bb; o_.y = a1[s] + bb;            \
                *(float2*)(out + (size_t)gy * WO + gx) = o_;                \
            }                                                               \
            a0[s] = 0.f; a1[s] = 0.f;                                       \
        }                                                                   \
    }

    // ---- phase A: stage rows 0..9 (chunks k=0..4); one exposed drain ----
    stage(0, 5);
    __syncthreads();

    // ---- issue phase-B stage (rows 10..13, k=5..6), fire-and-forget ----
    stage(5, 7);

    // ---- compute A: rows 0..9 (~2000 cyc, covers stage-B HBM latency) ----
    #pragma unroll
    for (int r = 0; r < 10; ++r) DOROW(r)

    __syncthreads();   // vmcnt(0) drain of stage-B: aged a full phase -> ~free

    // ---- compute B: rows 10..13 ----
    #pragma unroll
    for (int r = 10; r < 14; ++r) DOROW(r)

    #undef DOROW
}

extern "C" void kernel_launch(void* const* d_in, const int* in_sizes, int n_in,
                              void* d_out, int out_size, void* d_ws, size_t ws_size,
                              hipStream_t stream) {
    const float* x = (const float*)d_in[0];
    const float* w = (const float*)d_in[1];
    const float* b = (const float*)d_in[2];
    float* out = (float*)d_out;
    // x: ceil(4090/506) = 9 stripes; y: ceil(4090/8) = 512 segments
    dim3 grid(9, 512);
    conv7x7<<<grid, 256, 0, stream>>>(x, w, b, out);
}

// Round 14
// 88.959 us; speedup vs baseline: 1.1640x; 1.1640x over previous
//
#include <hip/hip_runtime.h>

#define WI 4096
#define HI 4096
#define WO 4090
#define HO 4090
#define TH 9             // output rows per block
#define IH 15            // staged input rows
#define IWP 520          // floats per LDS row (518 needed, 16B multiple)
#define CPR 130          // 16-byte chunks per LDS row
#define ACH (11*CPR)     // phase-A chunks (input rows 0..10) = 1430
#define NCH (IH*CPR)     // total chunks                      = 1950

__device__ __forceinline__ void gl_lds16(const float* g, float* l) {
    __builtin_amdgcn_global_load_lds(
        (const __attribute__((address_space(1))) void*)g,
        (__attribute__((address_space(3))) void*)l, 16, 0, 0);
}

__global__ __launch_bounds__(256, 5) void conv7x7(
    const float* __restrict__ x, const float* __restrict__ wgt,
    const float* __restrict__ bias, float* __restrict__ out)
{
    __shared__ float lds[IH * IWP];   // 31,200 B -> 5 blocks/CU (20 waves)

    const int tid = threadIdx.x;
    const int x0  = blockIdx.x * 512;     // ALIGNED stripes (R13 lesson)
    const int y0  = blockIdx.y * TH;

    // weights + bias: uniform addresses -> SGPR-resident scalar loads
    float Wt[49];
    #pragma unroll
    for (int i = 0; i < 49; ++i) Wt[i] = wgt[i];
    const float bb = bias[0];

    const int cx  = 2 * tid;          // local first output col
    const int gx  = x0 + cx;          // global first output col
    const bool stok = (gx + 1 < WO);  // per-lane pair-store mask

    // stage chunks [c0,c0+n): chunk c -> LDS floats [4c,4c+4), src row c/130,
    // col 4*(c%130). LDS dest per wave-instr = uniform base + lane*16 (linear,
    // as required); per-lane global src, clamped (clamped data only ever
    // feeds masked-off outputs).
    auto stage = [&](int c0, int n) {
        for (int c = c0 + tid; c < c0 + n; c += 256) {
            const int rr = c / CPR;            // magic-mul div
            const int c4 = c - rr * CPR;
            int gy = y0 + rr;       gy  = gy  < HI ? gy : HI - 1;
            int gxs = x0 + c4 * 4;  gxs = gxs <= WI - 4 ? gxs : WI - 4;
            gl_lds16(x + (size_t)gy * WI + gxs, lds + c * 4);
        }
    };

    float a0[7], a1[7];
    #pragma unroll
    for (int s = 0; s < 7; ++s) { a0[s] = 0.f; a1[s] = 0.f; }

    // fully-static row step: 4x ds_read_b64 + 98 FMA (+1 store from r>=6)
    #define DOROW(r)                                                        \
    {                                                                       \
        const float* lrow_ = lds + (r) * IWP + cx;                          \
        const float2 q0 = *(const float2*)(lrow_ + 0);                      \
        const float2 q1 = *(const float2*)(lrow_ + 2);                      \
        const float2 q2 = *(const float2*)(lrow_ + 4);                      \
        const float2 q3 = *(const float2*)(lrow_ + 6);                      \
        const float f_[8] = {q0.x,q0.y,q1.x,q1.y,q2.x,q2.y,q3.x,q3.y};      \
        _Pragma("unroll")                                                   \
        for (int ky = 0; ky < 7; ++ky) {                                    \
            const int oy = (r) - ky;               /* static */             \
            if (oy >= 0 && oy < TH) {                                       \
                const int s = oy % 7;              /* static */             \
                _Pragma("unroll")                                           \
                for (int kx = 0; kx < 7; ++kx) {                            \
                    const float w_ = Wt[ky * 7 + kx];                       \
                    a0[s] += w_ * f_[kx];                                   \
                    a1[s] += w_ * f_[kx + 1];                               \
                }                                                           \
            }                                                               \
        }                                                                   \
        if ((r) >= 6) {                            /* static */             \
            const int oy = (r) - 6;                                         \
            const int s  = oy % 7;                 /* static */             \
            const int gy = y0 + oy;                                         \
            if (stok && gy < HO) {                                          \
                float2 o_; o_.x = a0[s] + bb; o_.y = a1[s] + bb;            \
                *(float2*)(out + (size_t)gy * WO + gx) = o_;                \
            }                                                               \
            a0[s] = 0.f; a1[s] = 0.f;                                       \
        }                                                                   \
    }

    // ---- phase A: stage input rows 0..10; exposed drain once per block ----
    stage(0, ACH);
    __syncthreads();

    // ---- issue phase-B stage (rows 11..14), fire-and-forget ----
    stage(ACH, NCH - ACH);

    // ---- compute A: rows 0..10 (~2600 cyc, covers stage-B HBM latency) ----
    #pragma unroll
    for (int r = 0; r < 11; ++r) DOROW(r)

    __syncthreads();   // vmcnt(0) drain of stage-B: aged a full phase -> ~free

    // ---- compute B: rows 11..14 ----
    #pragma unroll
    for (int r = 11; r < 15; ++r) DOROW(r)

    #undef DOROW
}

extern "C" void kernel_launch(void* const* d_in, const int* in_sizes, int n_in,
                              void* d_out, int out_size, void* d_ws, size_t ws_size,
                              hipStream_t stream) {
    const float* x = (const float*)d_in[0];
    const float* w = (const float*)d_in[1];
    const float* b = (const float*)d_in[2];
    float* out = (float*)d_out;
    // x: 8 stripes x 512 cols (last stripe masks cols >= 4090)
    // y: ceil(4090/9) = 455 segments
    dim3 grid(8, 455);
    conv7x7<<<grid, 256, 0, stream>>>(x, w, b, out);
}

// Round 15
// 88.571 us; speedup vs baseline: 1.1691x; 1.0044x over previous
//
#include <hip/hip_runtime.h>

#define WI 4096
#define HI 4096
#define WO 4090
#define HO 4090
#define STRIP 32         // output rows per block = 4 phases x 8
#define GR 8             // rows per group/slot
#define IWP 520          // floats per LDS row (518 needed, 16B multiple)
#define CPR 130          // 16B chunks per row
#define SLOTF (GR*IWP)   // 4160 floats per ring slot
#define GCH (GR*CPR)     // 1040 chunks per group

__device__ __forceinline__ void gl_lds16(const float* g, float* l) {
    __builtin_amdgcn_global_load_lds(
        (const __attribute__((address_space(1))) void*)g,
        (__attribute__((address_space(3))) void*)l, 16, 0, 0);
}

__global__ __launch_bounds__(256, 3) void conv7x7(
    const float* __restrict__ x, const float* __restrict__ wgt,
    const float* __restrict__ bias, float* __restrict__ out)
{
    __shared__ float ring[3 * SLOTF];   // 49,920 B -> 3 blocks/CU

    const int tid = threadIdx.x;
    const int x0  = blockIdx.x * 512;   // aligned 512-wide stripes (proven)
    const int y0  = blockIdx.y * STRIP;

    // weights + bias: uniform addresses -> SGPR-resident
    float Wt[49];
    #pragma unroll
    for (int i = 0; i < 49; ++i) Wt[i] = wgt[i];
    const float bb = bias[0];

    const int cx  = 2 * tid;
    const int gx  = x0 + cx;
    const bool stok = (gx + 1 < WO);    // pair-store mask (R11-identical)

    // stage group g (input rows y0+8g .. +7) into ring slot `slot`.
    // chunk c -> LDS floats [slot*SLOTF + 4c, +4), src row c/130, col 4*(c%130).
    // LDS dest per wave-instr = uniform base + lane*16 (linear, required);
    // per-lane clamped global src only ever feeds masked-off outputs.
    #define STAGE(g, slot)                                                   \
    {                                                                        \
        _Pragma("unroll")                                                    \
        for (int k = 0; k < 4; ++k) {                                        \
            const int c  = tid + (k << 8);                                   \
            const int rr = c / CPR;                                          \
            const int c4 = c - rr * CPR;                                     \
            int gy = y0 + 8 * (g) + rr;  gy  = gy  < HI ? gy : HI - 1;       \
            int gxs = x0 + c4 * 4;       gxs = gxs <= WI - 4 ? gxs : WI - 4; \
            gl_lds16(x + (size_t)gy * WI + gxs,                              \
                     ring + (slot) * SLOTF + c * 4);                         \
        }                                                                    \
        if (tid < GCH - 1024) {                                              \
            const int c  = 1024 + tid;                                       \
            const int rr = c / CPR;                                          \
            const int c4 = c - rr * CPR;                                     \
            int gy = y0 + 8 * (g) + rr;  gy  = gy  < HI ? gy : HI - 1;       \
            int gxs = x0 + c4 * 4;       gxs = gxs <= WI - 4 ? gxs : WI - 4; \
            gl_lds16(x + (size_t)gy * WI + gxs,                              \
                     ring + (slot) * SLOTF + c * 4);                         \
        }                                                                    \
    }

    // one phase: 8 output rows, reads 14 input rows from slots sa/sb (static)
    #define PHASE(p, sa, sb)                                                 \
    {                                                                        \
        if ((p) < 3) STAGE((p) + 2, ((p) + 2) % 3)                           \
        float acc[8][2];                                                     \
        _Pragma("unroll")                                                    \
        for (int o = 0; o < 8; ++o) { acc[o][0] = 0.f; acc[o][1] = 0.f; }    \
        _Pragma("unroll")                                                    \
        for (int j = 0; j < 14; ++j) {                                       \
            const float* lrow_ = ring +                                      \
                ((j) < 8 ? (sa) * SLOTF + (j) * IWP                          \
                         : (sb) * SLOTF + ((j) - 8) * IWP) + cx;             \
            const float2 q0 = *(const float2*)(lrow_ + 0);                   \
            const float2 q1 = *(const float2*)(lrow_ + 2);                   \
            const float2 q2 = *(const float2*)(lrow_ + 4);                   \
            const float2 q3 = *(const float2*)(lrow_ + 6);                   \
            const float f_[8] = {q0.x,q0.y,q1.x,q1.y,q2.x,q2.y,q3.x,q3.y};   \
            _Pragma("unroll")                                                \
            for (int ky = 0; ky < 7; ++ky) {                                 \
                const int oy = j - ky;                 /* static */          \
                if (oy >= 0 && oy < 8) {                                     \
                    _Pragma("unroll")                                        \
                    for (int kx = 0; kx < 7; ++kx) {                         \
                        const float w_ = Wt[ky * 7 + kx];                    \
                        acc[oy][0] += w_ * f_[kx];                           \
                        acc[oy][1] += w_ * f_[kx + 1];                       \
                    }                                                        \
                }                                                            \
            }                                                                \
        }                                                                    \
        _Pragma("unroll")                                                    \
        for (int o = 0; o < 8; ++o) {                                        \
            const int gy = y0 + 8 * (p) + o;                                 \
            if (stok && gy < HO) {                                           \
                float2 o_; o_.x = acc[o][0] + bb; o_.y = acc[o][1] + bb;     \
                *(float2*)(out + (size_t)gy * WO + gx) = o_;                 \
            }                                                                \
        }                                                                    \
        __syncthreads();                                                     \
    }

    // prologue: groups 0,1 staged; ONE exposed drain per block
    STAGE(0, 0) STAGE(1, 1)
    __syncthreads();

    PHASE(0, 0, 1)
    PHASE(1, 1, 2)
    PHASE(2, 2, 0)
    PHASE(3, 0, 1)

    #undef PHASE
    #undef STAGE
}

extern "C" void kernel_launch(void* const* d_in, const int* in_sizes, int n_in,
                              void* d_out, int out_size, void* d_ws, size_t ws_size,
                              hipStream_t stream) {
    const float* x = (const float*)d_in[0];
    const float* w = (const float*)d_in[1];
    const float* b = (const float*)d_in[2];
    float* out = (float*)d_out;
    // 8 stripes x 512 cols; 128 strips x 32 rows = 4096 >= 4090.
    // 1024 blocks = 4 per CU sequential at 3 resident -> balanced.
    dim3 grid(8, 128);
    conv7x7<<<grid, 256, 0, stream>>>(x, w, b, out);
}

// Round 16
// 38.753 us; speedup vs baseline: 2.6720x; 2.2856x over previous
//
#include <hip/hip_runtime.h>

#define WI 4096
#define HI 4096
#define WO 4090
#define HO 4090
#define TH 9             // output rows per block
#define IH 15            // staged input rows
#define IWP 520          // floats per LDS row (518 needed, 16B multiple)
#define CPR 130          // 16-byte chunks per LDS row
#define ACH (11*CPR)     // phase-A chunks (input rows 0..10) = 1430
#define NCH (IH*CPR)     // total chunks                      = 1950

__device__ __forceinline__ void gl_lds16(const float* g, float* l) {
    __builtin_amdgcn_global_load_lds(
        (const __attribute__((address_space(1))) void*)g,
        (__attribute__((address_space(3))) void*)l, 16, 0, 0);
}

__global__ __launch_bounds__(256, 4) void conv7x7(
    const float* __restrict__ x, const float* __restrict__ wgt,
    const float* __restrict__ bias, float* __restrict__ out)
{
    __shared__ float lds[IH * IWP];   // 31,200 B -> 5 blocks/CU by LDS

    const int tid = threadIdx.x;
    const int x0  = blockIdx.x * 512;     // ALIGNED 512-wide stripes (proven)
    const int y0  = blockIdx.y * TH;

    // weights + bias: uniform addresses -> SGPR-resident scalar loads
    float Wt[49];
    #pragma unroll
    for (int i = 0; i < 49; ++i) Wt[i] = wgt[i];
    const float bb = bias[0];

    const int cx  = 2 * tid;          // local first output col
    const int gx  = x0 + cx;          // global first output col
    const bool stok = (gx + 1 < WO);  // per-lane pair-store mask

    // stage chunks [c0,c0+n): chunk c -> LDS floats [4c,4c+4), src row c/130,
    // col 4*(c%130). LDS dest per wave-instr = uniform base + lane*16 (linear,
    // as required); per-lane global src, clamped (clamped data only ever
    // feeds masked-off outputs).
    auto stage = [&](int c0, int n) {
        for (int c = c0 + tid; c < c0 + n; c += 256) {
            const int rr = c / CPR;            // magic-mul div
            const int c4 = c - rr * CPR;
            int gy = y0 + rr;       gy  = gy  < HI ? gy : HI - 1;
            int gxs = x0 + c4 * 4;  gxs = gxs <= WI - 4 ? gxs : WI - 4;
            gl_lds16(x + (size_t)gy * WI + gxs, lds + c * 4);
        }
    };

    float a0[7], a1[7];
    #pragma unroll
    for (int s = 0; s < 7; ++s) { a0[s] = 0.f; a1[s] = 0.f; }

    // fully-static row step: 4x ds_read_b64 + 98 FMA (+1 store from r>=6)
    #define DOROW(r)                                                        \
    {                                                                       \
        const float* lrow_ = lds + (r) * IWP + cx;                          \
        const float2 q0 = *(const float2*)(lrow_ + 0);                      \
        const float2 q1 = *(const float2*)(lrow_ + 2);                      \
        const float2 q2 = *(const float2*)(lrow_ + 4);                      \
        const float2 q3 = *(const float2*)(lrow_ + 6);                      \
        const float f_[8] = {q0.x,q0.y,q1.x,q1.y,q2.x,q2.y,q3.x,q3.y};      \
        _Pragma("unroll")                                                   \
        for (int ky = 0; ky < 7; ++ky) {                                    \
            const int oy = (r) - ky;               /* static */             \
            if (oy >= 0 && oy < TH) {                                       \
                const int s = oy % 7;              /* static */             \
                _Pragma("unroll")                                           \
                for (int kx = 0; kx < 7; ++kx) {                            \
                    const float w_ = Wt[ky * 7 + kx];                       \
                    a0[s] += w_ * f_[kx];                                   \
                    a1[s] += w_ * f_[kx + 1];                               \
                }                                                           \
            }                                                               \
        }                                                                   \
        if ((r) >= 6) {                            /* static */             \
            const int oy = (r) - 6;                                         \
            const int s  = oy % 7;                 /* static */             \
            const int gy = y0 + oy;                                         \
            if (stok && gy < HO) {                                          \
                float2 o_; o_.x = a0[s] + bb; o_.y = a1[s] + bb;            \
                *(float2*)(out + (size_t)gy * WO + gx) = o_;                \
            }                                                               \
            a0[s] = 0.f; a1[s] = 0.f;                                       \
        }                                                                   \
    }

    // ---- phase A: stage input rows 0..10; exposed drain once per block ----
    stage(0, ACH);
    __syncthreads();

    // ---- issue phase-B stage (rows 11..14), fire-and-forget ----
    stage(ACH, NCH - ACH);

    // ---- compute A: rows 0..10 (~2600 cyc, covers stage-B HBM latency) ----
    #pragma unroll
    for (int r = 0; r < 11; ++r) DOROW(r)

    __syncthreads();   // vmcnt(0) drain of stage-B: aged a full phase -> ~free

    // ---- compute B: rows 11..14 ----
    #pragma unroll
    for (int r = 11; r < 15; ++r) DOROW(r)

    #undef DOROW
}

extern "C" void kernel_launch(void* const* d_in, const int* in_sizes, int n_in,
                              void* d_out, int out_size, void* d_ws, size_t ws_size,
                              hipStream_t stream) {
    const float* x = (const float*)d_in[0];
    const float* w = (const float*)d_in[1];
    const float* b = (const float*)d_in[2];
    float* out = (float*)d_out;
    // x: 8 stripes x 512 cols (last stripe masks cols >= 4090)
    // y: ceil(4090/9) = 455 segments
    dim3 grid(8, 455);
    conv7x7<<<grid, 256, 0, stream>>>(x, w, b, out);
}

// Round 17
// 36.808 us; speedup vs baseline: 2.8132x; 1.0528x over previous
//
#include <hip/hip_runtime.h>

#define WI 4096
#define HI 4096
#define WO 4090
#define HO 4090
#define TH 12            // output rows per block
#define IH 18            // staged input rows
#define IWP 520          // floats per LDS row (518 needed, 16B multiple)
#define CPR 130          // 16-byte chunks per LDS row
#define ACH (7*CPR)      // phase-A chunks (input rows 0..6)   = 910
#define BCH (14*CPR)     // A+B chunks     (input rows 0..13)  = 1820
#define NCH (IH*CPR)     // total chunks                       = 2340

__device__ __forceinline__ void gl_lds16(const float* g, float* l) {
    __builtin_amdgcn_global_load_lds(
        (const __attribute__((address_space(1))) void*)g,
        (__attribute__((address_space(3))) void*)l, 16, 0, 0);
}

__global__ __launch_bounds__(256, 4) void conv7x7(
    const float* __restrict__ x, const float* __restrict__ wgt,
    const float* __restrict__ bias, float* __restrict__ out)
{
    __shared__ float lds[IH * IWP];   // 37,440 B -> 4 blocks/CU (16 waves)

    const int tid = threadIdx.x;
    const int x0  = blockIdx.x * 512;     // aligned 512-wide stripes (proven)
    const int y0  = blockIdx.y * TH;

    // weights + bias: uniform addresses -> SGPR-resident scalar loads
    float Wt[49];
    #pragma unroll
    for (int i = 0; i < 49; ++i) Wt[i] = wgt[i];
    const float bb = bias[0];

    const int cx  = 2 * tid;          // local first output col
    const int gx  = x0 + cx;          // global first output col
    const bool stok = (gx + 1 < WO);  // per-lane pair-store mask

    // stage chunks [c0,c0+n): chunk c -> LDS floats [4c,4c+4), src row c/130,
    // col 4*(c%130). LDS dest per wave-instr = uniform base + lane*16 (linear,
    // as required); per-lane global src, clamped (clamped data only ever
    // feeds masked-off outputs).
    auto stage = [&](int c0, int n) {
        for (int c = c0 + tid; c < c0 + n; c += 256) {
            const int rr = c / CPR;            // magic-mul div
            const int c4 = c - rr * CPR;
            int gy = y0 + rr;       gy  = gy  < HI ? gy : HI - 1;
            int gxs = x0 + c4 * 4;  gxs = gxs <= WI - 4 ? gxs : WI - 4;
            gl_lds16(x + (size_t)gy * WI + gxs, lds + c * 4);
        }
    };

    float a0[7], a1[7];
    #pragma unroll
    for (int s = 0; s < 7; ++s) { a0[s] = 0.f; a1[s] = 0.f; }

    // fully-static row step: 4x ds_read_b64 + 98 FMA (+1 store from r>=6)
    #define DOROW(r)                                                        \
    {                                                                       \
        const float* lrow_ = lds + (r) * IWP + cx;                          \
        const float2 q0 = *(const float2*)(lrow_ + 0);                      \
        const float2 q1 = *(const float2*)(lrow_ + 2);                      \
        const float2 q2 = *(const float2*)(lrow_ + 4);                      \
        const float2 q3 = *(const float2*)(lrow_ + 6);                      \
        const float f_[8] = {q0.x,q0.y,q1.x,q1.y,q2.x,q2.y,q3.x,q3.y};      \
        _Pragma("unroll")                                                   \
        for (int ky = 0; ky < 7; ++ky) {                                    \
            const int oy = (r) - ky;               /* static */             \
            if (oy >= 0 && oy < TH) {                                       \
                const int s = oy % 7;              /* static */             \
                _Pragma("unroll")                                           \
                for (int kx = 0; kx < 7; ++kx) {                            \
                    const float w_ = Wt[ky * 7 + kx];                       \
                    a0[s] += w_ * f_[kx];                                   \
                    a1[s] += w_ * f_[kx + 1];                               \
                }                                                           \
            }                                                               \
        }                                                                   \
        if ((r) >= 6) {                            /* static */             \
            const int oy = (r) - 6;                                         \
            const int s  = oy % 7;                 /* static */             \
            const int gy = y0 + oy;                                         \
            if (stok && gy < HO) {                                          \
                float2 o_; o_.x = a0[s] + bb; o_.y = a1[s] + bb;            \
                *(float2*)(out + (size_t)gy * WO + gx) = o_;                \
            }                                                               \
            a0[s] = 0.f; a1[s] = 0.f;                                       \
        }                                                                   \
    }

    // ---- phase A: stage rows 0..6 (min to start); one exposed drain ----
    stage(0, ACH);
    __syncthreads();

    // ---- issue stage-B (rows 7..13), fire-and-forget ----
    stage(ACH, BCH - ACH);

    // ---- compute rows 0..6 (~1600 cyc, covers stage-B HBM latency) ----
    #pragma unroll
    for (int r = 0; r < 7; ++r) DOROW(r)

    __syncthreads();   // drains stage-B: aged a full compute phase -> ~free

    // ---- issue stage-C (rows 14..17), fire-and-forget ----
    stage(BCH, NCH - BCH);

    // ---- compute rows 7..13 (covers stage-C) ----
    #pragma unroll
    for (int r = 7; r < 14; ++r) DOROW(r)

    __syncthreads();   // drains stage-C: aged a full compute phase -> ~free

    // ---- compute rows 14..17 ----
    #pragma unroll
    for (int r = 14; r < 18; ++r) DOROW(r)

    #undef DOROW
}

extern "C" void kernel_launch(void* const* d_in, const int* in_sizes, int n_in,
                              void* d_out, int out_size, void* d_ws, size_t ws_size,
                              hipStream_t stream) {
    const float* x = (const float*)d_in[0];
    const float* w = (const float*)d_in[1];
    const float* b = (const float*)d_in[2];
    float* out = (float*)d_out;
    // x: 8 stripes x 512 cols (last stripe masks cols >= 4090)
    // y: ceil(4090/12) = 341 segments
    dim3 grid(8, 341);
    conv7x7<<<grid, 256, 0, stream>>>(x, w, b, out);
}

// Round 18
// 34.341 us; speedup vs baseline: 3.0153x; 1.0719x over previous
//
#include <hip/hip_runtime.h>

#define WI 4096
#define HI 4096
#define WO 4090
#define HO 4090
#define TH 16              // output rows per block
#define IH 22              // staged input rows (TH + 6)
#define LW 536             // bf16 per LDS row (512 + halo/pad; stride 1072B)
#define CPR4 134           // float4 chunks per row (LW/4)
#define NCHK (IH*CPR4)     // 2948 chunks

typedef __attribute__((ext_vector_type(8))) short bf16x8;
typedef __attribute__((ext_vector_type(4))) float f32x4;

__device__ __forceinline__ unsigned short f2bf(float f) {
    union { float f; unsigned u; } v; v.f = f;
    unsigned r = v.u + 0x7FFFu + ((v.u >> 16) & 1u);   // RNE
    return (unsigned short)(r >> 16);
}

__global__ __launch_bounds__(256, 4) void conv7x7(
    const float* __restrict__ x, const float* __restrict__ wgt,
    const float* __restrict__ bias, float* __restrict__ out)
{
    __shared__ unsigned short tile[IH * LW];   // 23,584 B
    __shared__ float wlds[49];

    const int tid = threadIdx.x;
    const int x0  = blockIdx.x * 512;          // aligned 512-wide stripes
    const int y0  = blockIdx.y * TH;

    if (tid < 49) wlds[tid] = wgt[tid];
    const float bb = bias[0];

    // ---- stage: fp32 global -> RNE bf16 LDS ----
    #pragma unroll
    for (int k = 0; k < 12; ++k) {
        const int c = tid + (k << 8);
        if (c < NCHK) {
            const int row = c / CPR4;              // magic-mul div
            const int c4  = c - row * CPR4;
            int gy  = y0 + row;       gy  = gy  < HI ? gy : HI - 1;
            int gxs = x0 + (c4 << 2); gxs = gxs <= WI - 4 ? gxs : WI - 4;
            const float4 q = *(const float4*)(x + (size_t)gy * WI + gxs);
            unsigned u0 = (unsigned)f2bf(q.x) | ((unsigned)f2bf(q.y) << 16);
            unsigned u1 = (unsigned)f2bf(q.z) | ((unsigned)f2bf(q.w) << 16);
            *(uint2*)&tile[row * LW + (c4 << 2)] = make_uint2(u0, u1);
        }
    }
    __syncthreads();

    // ---- per-lane banded B fragments: B_ky[k][n] = W[ky][k-n], 0<=k-n<7 ----
    const int n   = tid & 15;          // B col / A row / D col (lane&15)
    const int kb8 = ((tid >> 4) & 3) << 3;   // k-block base (lane>>4)*8
    bf16x8 Bf[7];
    #pragma unroll
    for (int ky = 0; ky < 7; ++ky) {
        #pragma unroll
        for (int j = 0; j < 8; ++j) {
            const int t = kb8 + j - n;                     // tap index
            const float wv = (t >= 0 && t < 7) ? wlds[ky * 7 + t] : 0.f;
            Bf[ky][j] = (short)f2bf(wv);
        }
    }

    // ---- compute: 8 x-tiles per wave, pairs for ILP; 7 MFMA per tile ----
    const int wcol  = (tid >> 6) << 7;       // wave col base 0/128/256/384
    const int growb = y0 + (((tid >> 4) & 3) << 2);   // D row base

    #pragma unroll
    for (int tp = 0; tp < 4; ++tp) {
        const int xt0 = wcol + (tp << 5);
        const int xt1 = xt0 + 16;
        f32x4 acc0 = {0.f, 0.f, 0.f, 0.f};
        f32x4 acc1 = {0.f, 0.f, 0.f, 0.f};
        #pragma unroll
        for (int ky = 0; ky < 7; ++ky) {
            const unsigned short* rp = &tile[(ky + n) * LW + kb8];
            const bf16x8 av0 = *(const bf16x8*)(rp + xt0);   // 16B aligned
            const bf16x8 av1 = *(const bf16x8*)(rp + xt1);
            acc0 = __builtin_amdgcn_mfma_f32_16x16x32_bf16(av0, Bf[ky], acc0, 0, 0, 0);
            acc1 = __builtin_amdgcn_mfma_f32_16x16x32_bf16(av1, Bf[ky], acc1, 0, 0, 0);
        }
        const int gc0 = x0 + xt0 + n;
        const int gc1 = gc0 + 16;
        #pragma unroll
        for (int v = 0; v < 4; ++v) {
            const int grow = growb + v;
            if (grow < HO) {
                if (gc0 < WO) out[(size_t)grow * WO + gc0] = acc0[v] + bb;
                if (gc1 < WO) out[(size_t)grow * WO + gc1] = acc1[v] + bb;
            }
        }
    }
}

extern "C" void kernel_launch(void* const* d_in, const int* in_sizes, int n_in,
                              void* d_out, int out_size, void* d_ws, size_t ws_size,
                              hipStream_t stream) {
    const float* x = (const float*)d_in[0];
    const float* w = (const float*)d_in[1];
    const float* b = (const float*)d_in[2];
    float* out = (float*)d_out;
    // x: 8 stripes x 512 cols; y: ceil(4090/16) = 256 segments
    dim3 grid(8, 256);
    conv7x7<<<grid, 256, 0, stream>>>(x, w, b, out);
}

// Round 19
// 30.519 us; speedup vs baseline: 3.3929x; 1.1252x over previous
//
#include <hip/hip_runtime.h>

#define WI 4096
#define HI 4096
#define WO 4090
#define HO 4090
#define TH 16              // output rows per block
#define IH 22              // staged input rows (TH + 6)
#define LW 536             // bf16 per LDS row (512 + halo/pad; stride 1072B)
#define CPR4 134           // float4 chunks per row (LW/4)
#define NCHK (IH*CPR4)     // 2948 chunks

typedef __attribute__((ext_vector_type(8))) short bf16x8;
typedef __attribute__((ext_vector_type(4))) float f32x4;

__device__ __forceinline__ unsigned short f2bf(float f) {
    union { float f; unsigned u; } v; v.f = f;
    unsigned r = v.u + 0x7FFFu + ((v.u >> 16) & 1u);   // RNE
    return (unsigned short)(r >> 16);
}

__global__ __launch_bounds__(256, 6) void conv7x7(
    const float* __restrict__ x, const float* __restrict__ wgt,
    const float* __restrict__ bias, float* __restrict__ out)
{
    __shared__ unsigned short tile[IH * LW];   // 23,584 B -> 6 blocks/CU
    __shared__ float wlds[49];

    const int tid = threadIdx.x;
    const int x0  = blockIdx.x * 512;          // aligned 512-wide stripes
    const int y0  = blockIdx.y * TH;

    if (tid < 49) wlds[tid] = wgt[tid];
    const float bb = bias[0];

    // ---- stage: ALL 12 loads issued first (in-flight together), then cvt ----
    float4 qv[12];
    int   crow[12], ccol[12];
    #pragma unroll
    for (int k = 0; k < 12; ++k) {
        const int c = tid + (k << 8);
        const int row = c / CPR4;              // magic-mul div
        const int c4  = c - row * CPR4;
        const int rowc = (c < NCHK) ? row : (IH - 1);
        int gy  = y0 + rowc;      gy  = gy  < HI ? gy : HI - 1;
        int gxs = x0 + (c4 << 2); gxs = gxs <= WI - 4 ? gxs : WI - 4;
        crow[k] = rowc; ccol[k] = (c4 << 2);
        qv[k] = *(const float4*)(x + (size_t)gy * WI + gxs);
    }
    #pragma unroll
    for (int k = 0; k < 12; ++k) {
        const int c = tid + (k << 8);
        if (c < NCHK) {
            unsigned u0 = (unsigned)f2bf(qv[k].x) | ((unsigned)f2bf(qv[k].y) << 16);
            unsigned u1 = (unsigned)f2bf(qv[k].z) | ((unsigned)f2bf(qv[k].w) << 16);
            *(uint2*)&tile[crow[k] * LW + ccol[k]] = make_uint2(u0, u1);
        }
    }
    __syncthreads();

    // ---- per-lane banded B fragments: B_ky[k][n] = W[ky][k-n], 0<=k-n<7 ----
    const int n   = tid & 15;                // B col / D col (lane&15)
    const int kb8 = ((tid >> 4) & 3) << 3;   // k-block base (lane>>4)*8
    bf16x8 Bf[7];
    #pragma unroll
    for (int ky = 0; ky < 7; ++ky) {
        #pragma unroll
        for (int j = 0; j < 8; ++j) {
            const int t = kb8 + j - n;                     // tap index
            const float wv = (t >= 0 && t < 7) ? wlds[ky * 7 + t] : 0.f;
            Bf[ky][j] = (short)f2bf(wv);
        }
    }

    // ---- compute: 8 x-tiles per wave, pairs for ILP; 7 MFMA per tile ----
    const int wcol  = (tid >> 6) << 7;       // wave col base 0/128/256/384
    const int growb = y0 + (((tid >> 4) & 3) << 2);   // D row base

    #pragma unroll
    for (int tp = 0; tp < 4; ++tp) {
        const int xt0 = wcol + (tp << 5);
        const int xt1 = xt0 + 16;
        f32x4 acc0 = {0.f, 0.f, 0.f, 0.f};
        f32x4 acc1 = {0.f, 0.f, 0.f, 0.f};
        #pragma unroll
        for (int ky = 0; ky < 7; ++ky) {
            const unsigned short* rp = &tile[(ky + n) * LW + kb8];
            const bf16x8 av0 = *(const bf16x8*)(rp + xt0);   // 16B aligned
            const bf16x8 av1 = *(const bf16x8*)(rp + xt1);
            acc0 = __builtin_amdgcn_mfma_f32_16x16x32_bf16(av0, Bf[ky], acc0, 0, 0, 0);
            acc1 = __builtin_amdgcn_mfma_f32_16x16x32_bf16(av1, Bf[ky], acc1, 0, 0, 0);
        }
        const int gc0 = x0 + xt0 + n;
        const int gc1 = gc0 + 16;
        #pragma unroll
        for (int v = 0; v < 4; ++v) {
            const int grow = growb + v;
            if (grow < HO) {
                if (gc0 < WO) out[(size_t)grow * WO + gc0] = acc0[v] + bb;
                if (gc1 < WO) out[(size_t)grow * WO + gc1] = acc1[v] + bb;
            }
        }
    }
}

extern "C" void kernel_launch(void* const* d_in, const int* in_sizes, int n_in,
                              void* d_out, int out_size, void* d_ws, size_t ws_size,
                              hipStream_t stream) {
    const float* x = (const float*)d_in[0];
    const float* w = (const float*)d_in[1];
    const float* b = (const float*)d_in[2];
    float* out = (float*)d_out;
    // x: 8 stripes x 512 cols; y: ceil(4090/16) = 256 segments
    dim3 grid(8, 256);
    conv7x7<<<grid, 256, 0, stream>>>(x, w, b, out);
}